// Round 7
// baseline (6022.539 us; speedup 1.0000x reference)
//
#include <hip/hip_runtime.h>
#include <stdint.h>

// Problem constants (from reference)
#define S_WORDS 2048
#define LMAX    16
#define CE      256
#define WE      512
#define HDIM    1024
#define GC      1024   // 4*CE
#define GW      4096   // 4*HDIM
#define KW      768    // WE + CE
#define NWG_RNN 128    // recurrence WGs: 8 units each, 1 unit per wave
#define NWB_WIN 512    // fused wordin producer blocks (2 per 8-row group)
#define NMIR    4      // ring mirrors (fan-in reduction 128 -> 32 pollers/line)
#define RING_U64 (3 * HDIM)   // u64 per mirror (3 slots x 1024)

// Workspace layout (bytes) — high-water ~37.8 MiB (WT2w transposed copy removed;
// wordin now reads raw Wih_w directly)
#define IN_GATES_OFF 0                       // 2048*4096 fp32 = 33554432
#define LAST_OFF     33554432                // 2048*256 fp32  =  2097152
#define WT2C_OFF     35651584                // 256*1024 float2 = 2097152 (char weights)
// char_lstm's prefetch pipeline over-reads <=32 KB past WT2c (dead region; was
// WT2w). Ring mirrors + row-ready flags alias WT2c (dead after char_lstm;
// memset enqueued after char_lstm):
#define RING_OFF     WT2C_OFF                // 4 mirrors * 3 slots * 1024 u64 = 98304
#define FLAGS_OFF    (RING_OFF + NMIR * RING_U64 * 8)  // 256 u32 = 1024

typedef float f32x4 __attribute__((ext_vector_type(4)));

#define LD_AGENT(p) __hip_atomic_load((p), __ATOMIC_RELAXED, __HIP_MEMORY_SCOPE_AGENT)

static __device__ __forceinline__ float sigm(float x) { return 1.0f / (1.0f + __expf(-x)); }
static __device__ __forceinline__ float tanh_fast(float x) {
    float ax = fminf(fabsf(x), 15.0f);
    float e  = __expf(2.0f * ax);
    float t  = (e - 1.0f) / (e + 1.0f);
    return copysignf(t, x);
}

// ---------- prep: transposed k-major float2 pairs for coalesced char reads ----------
__global__ void prep_c_kernel(const float* __restrict__ Wih,
                              const float* __restrict__ Whh,
                              float2* __restrict__ WT2c) {
    int idx = blockIdx.x * blockDim.x + threadIdx.x;   // 256*1024
    if (idx >= 256 * GC) return;
    int kp = idx >> 10, row = idx & (GC - 1);
    int k = kp * 2;
    float2 v;
    if (k < CE) { v.x = Wih[row * CE + k];      v.y = Wih[row * CE + k + 1]; }
    else        { v.x = Whh[row * CE + k - CE]; v.y = Whh[row * CE + k - CE + 1]; }
    WT2c[idx] = v;
}

// ---------- char LSTM v13: gate-split + software-pipelined weight prefetch ----------
// Gate-split (v12, proven): thread (g, j) = (tid>>8, tid&255) owns gate g of
// unit j over the FULL K=512; TLP = 4 waves/SIMD; gates exchanged via padded
// LDS; elementwise + c-state thread-local (thread (g,j) owns words 2g, 2g+1).
// v13 adds explicit 2-deep rotating-register prefetch of the weight pairs:
// the next body's 4 float2 loads issue a full compute body (~128+ cy in-wave,
// ~4x wall-clock with 4 waves/SIMD) before use, hiding L2 latency that the
// compiler's unroll-2 didn't. Final iteration's prefetch over-reads <=32 KB
// past WT2c into the dead ex-WT2w workspace region (values never used).
__global__ void __launch_bounds__(1024, 1) char_lstm_kernel(
    const int* __restrict__ char_idxs,        // [2048][16]
    const int* __restrict__ char_lens,        // [2048]
    const float* __restrict__ char_emb,       // [256][256]
    const float* __restrict__ bih,            // [1024]
    const float* __restrict__ bhh,            // [1024]
    const float2* __restrict__ WT2c,          // [256][1024] k-pairs
    float* __restrict__ last_out)             // [2048][256]
{
    __shared__ float xh[8][2 * CE];           // 16 KB: [word][x(256) | h(256)]
    __shared__ float gex[4][256][9];          // 36 KB (pad 9 breaks bank aliasing)
    const int j = threadIdx.x & 255;          // unit
    const int g = threadIdx.x >> 8;           // gate 0..3; also word-pair owner
    const int wbase = blockIdx.x * 8;

    const float bias = bih[g * CE + j] + bhh[g * CE + j];   // own gate row only

    int len[2];
    float c[2] = {0.0f, 0.0f};
    len[0] = char_lens[wbase + 2 * g];
    len[1] = char_lens[wbase + 2 * g + 1];
    xh[2 * g][CE + j]     = 0.0f;             // h_{-1} = 0 (words 2g, 2g+1)
    xh[2 * g + 1][CE + j] = 0.0f;

    const float2* __restrict__ wrow = WT2c + g * CE + j;    // row g*256+j, kp-major

    for (int t = 0; t < LMAX; t++) {
        // gather x(t) for this thread's 2 words
        {
            int ci0 = char_idxs[(wbase + 2 * g) * LMAX + t];
            int ci1 = char_idxs[(wbase + 2 * g + 1) * LMAX + t];
            xh[2 * g][j]     = char_emb[ci0 * CE + j];
            xh[2 * g + 1][j] = char_emb[ci1 * CE + j];
        }
        __syncthreads();                      // B1: x(t) + h(t-1) visible

        float acc[8];
        #pragma unroll
        for (int w = 0; w < 8; w++) acc[w] = 0.0f;

        // 2-deep rotating prefetch: (c0,c1)=kq, (d0,d1)=kq+1 in flight->use
        float2 c0 = wrow[0 * GC], c1 = wrow[1 * GC];
        float2 d0 = wrow[2 * GC], d1 = wrow[3 * GC];
        const float2* wp = wrow + 4 * GC;
        for (int kq = 0; kq < 128; kq += 2) {
            float2 e0 = wp[0 * GC], e1 = wp[1 * GC];      // prefetch kq+2
            float2 f0 = wp[2 * GC], f1 = wp[3 * GC];      // prefetch kq+3
            wp += 4 * GC;                                  // (last iter: dead over-read)
            #pragma unroll
            for (int w = 0; w < 8; w++) {
                f32x4 xv = *(const f32x4*)&xh[w][4 * kq];  // wave-broadcast
                acc[w] = fmaf(c0.x, xv[0],
                         fmaf(c0.y, xv[1],
                         fmaf(c1.x, xv[2],
                         fmaf(c1.y, xv[3], acc[w]))));
            }
            #pragma unroll
            for (int w = 0; w < 8; w++) {
                f32x4 xv = *(const f32x4*)&xh[w][4 * kq + 4];
                acc[w] = fmaf(d0.x, xv[0],
                         fmaf(d0.y, xv[1],
                         fmaf(d1.x, xv[2],
                         fmaf(d1.y, xv[3], acc[w]))));
            }
            c0 = e0; c1 = e1; d0 = f0; d1 = f1;
        }

        #pragma unroll
        for (int w = 0; w < 8; w++) gex[g][j][w] = acc[w] + bias;
        __syncthreads();                      // B2: gex ready; all xh reads done

        // elementwise for words 2g, 2g+1 (c-state thread-local)
        #pragma unroll
        for (int ww = 0; ww < 2; ww++) {
            int w = 2 * g + ww;
            float gi = gex[0][j][w];
            float gf = gex[1][j][w];
            float gg = gex[2][j][w];
            float go = gex[3][j][w];
            float iv = sigm(gi);
            float fv = sigm(gf);
            float gv = tanhf(gg);
            float ov = sigm(go);
            c[ww] = fv * c[ww] + iv * gv;
            float h = ov * tanhf(c[ww]);
            xh[w][CE + j] = h;                // read by FMA(t+1) after B1(t+1)
            if (t == len[ww] - 1) last_out[(wbase + w) * CE + j] = h;
        }
    }
}

// ---------- fused word-LSTM: wordin producers + persistent recurrence (v9 rnn) ----------
// rnn = exact v9 (mirrored ring, single barrier, depth-1 incremental poll —
// proven 4.51-4.59 ms). wordin v13: reads RAW Wih_w directly (prep_w transposed
// copy deleted): each thread streams 4 rows sequentially as f32x4 (16 B/load,
// 64 B lines reused over 4 consecutive kq, per-wave working set fits L1).
// wordin has ~14x slack vs the rnn's consumption rate, so layout efficiency
// there is non-critical; removing prep_w deletes a serial prelude dispatch.
__global__ void __launch_bounds__(512, 2) fused_word_kernel(
    const float* __restrict__ Whh,            // [4096][1024]
    const int* __restrict__ word_idxs,
    const float* __restrict__ word_emb,       // [50000][512]
    const float* __restrict__ last,           // [2048][256]
    const float* __restrict__ Wih_w,          // [4096][768] raw
    const float* __restrict__ bih,            // [4096]
    const float* __restrict__ bhh,            // [4096]
    float* __restrict__ in_gates,             // [2048][4096]
    unsigned long long* __restrict__ ring,    // [NMIR][3][1024] tagged h
    unsigned int* __restrict__ flags,         // [256] row-group ready counters
    float* __restrict__ out)                  // [2048][1024]
{
    __shared__ float smem[8 * KW];            // 24 KB (wordin xh / rnn hbb overlay)
    const int tid = threadIdx.x;

    if (blockIdx.x >= NWG_RNN) {
        // ---------------- wordin producer role ----------------
        const int nb    = blockIdx.x - NWG_RNN;  // 0..511
        const int grp   = nb >> 1;               // 0..255: rows 8*grp..8*grp+8
        const int half  = nb & 1;
        const int jj    = tid & 255;
        const int gh    = tid >> 8;              // 0/1
        const int rb2   = half * 2 + gh;         // gate quarter 0..3
        const int wbase = grp * 8;
        float (*xh)[KW] = (float(*)[KW])smem;

        for (int w = 0; w < 8; w++) {
            int wi = word_idxs[wbase + w];
            xh[w][tid] = word_emb[(size_t)wi * WE + tid];
            if (tid < 256) xh[w][WE + tid] = last[(wbase + w) * CE + tid];
        }
        __syncthreads();

        // 4 sequential row streams (one per gate g of this thread's quarter)
        const float* wr0 = Wih_w + (size_t)(rb2 * GC + 0 * CE + jj) * KW;
        const float* wr1 = Wih_w + (size_t)(rb2 * GC + 1 * CE + jj) * KW;
        const float* wr2 = Wih_w + (size_t)(rb2 * GC + 2 * CE + jj) * KW;
        const float* wr3 = Wih_w + (size_t)(rb2 * GC + 3 * CE + jj) * KW;

        float acc[4][8];
        #pragma unroll
        for (int g = 0; g < 4; g++)
            #pragma unroll
            for (int w = 0; w < 8; w++) acc[g][w] = 0.0f;

        for (int kq = 0; kq < KW / 4; kq++) {    // 192 iters, 4 k each
            f32x4 w0 = *(const f32x4*)(wr0 + 4 * kq);
            f32x4 w1 = *(const f32x4*)(wr1 + 4 * kq);
            f32x4 w2 = *(const f32x4*)(wr2 + 4 * kq);
            f32x4 w3 = *(const f32x4*)(wr3 + 4 * kq);
            #pragma unroll
            for (int w = 0; w < 8; w++) {
                f32x4 xv = *(const f32x4*)&xh[w][4 * kq];
                acc[0][w] = fmaf(w0[0], xv[0], fmaf(w0[1], xv[1],
                            fmaf(w0[2], xv[2], fmaf(w0[3], xv[3], acc[0][w]))));
                acc[1][w] = fmaf(w1[0], xv[0], fmaf(w1[1], xv[1],
                            fmaf(w1[2], xv[2], fmaf(w1[3], xv[3], acc[1][w]))));
                acc[2][w] = fmaf(w2[0], xv[0], fmaf(w2[1], xv[1],
                            fmaf(w2[2], xv[2], fmaf(w2[3], xv[3], acc[2][w]))));
                acc[3][w] = fmaf(w3[0], xv[0], fmaf(w3[1], xv[1],
                            fmaf(w3[2], xv[2], fmaf(w3[3], xv[3], acc[3][w]))));
            }
        }

        // write-through (agent-scope) stores so the recurrence's bypassing loads
        // see them without any cache-coherence dance
        #pragma unroll
        for (int g = 0; g < 4; g++) {
            int row = rb2 * GC + g * CE + jj;
            float bias = bih[row] + bhh[row];
            #pragma unroll
            for (int w = 0; w < 8; w++)
                __hip_atomic_store(in_gates + (size_t)(wbase + w) * GW + row,
                                   acc[g][w] + bias,
                                   __ATOMIC_RELAXED, __HIP_MEMORY_SCOPE_AGENT);
        }
        __syncthreads();   // drains vmcnt -> all stores retired
        if (tid == 0)
            __hip_atomic_fetch_add(flags + grp, 1u,
                                   __ATOMIC_RELEASE, __HIP_MEMORY_SCOPE_AGENT);
        return;
    }

    // ---------------- recurrence role (EXACT v9) ----------------
    const int v = tid >> 6;                   // wave 0..7
    const int l = tid & 63;
    const int unit = blockIdx.x * 8 + v;
    float (*hbb)[HDIM] = (float(*)[HDIM])smem;   // [2][1024] in first 8 KB
    // this WG's poll mirror
    const unsigned long long* ring_my = ring + (size_t)(blockIdx.x & (NMIR - 1)) * RING_U64;

    // resident weights: all 4 gates of this wave's unit, full K
    // w[g][cc] = Whh[g*H+unit][cc*256 + l*4 .. +3]
    f32x4 w[4][4];
    #pragma unroll
    for (int g = 0; g < 4; g++)
        #pragma unroll
        for (int cc = 0; cc < 4; cc++)
            w[g][cc] = *(const f32x4*)(Whh + (size_t)(g * HDIM + unit) * HDIM
                                       + cc * 256 + l * 4);
    #pragma unroll
    for (int g = 0; g < 4; g++)
        #pragma unroll
        for (int cc = 0; cc < 4; cc++)
            asm volatile("" : "+v"(w[g][cc]));

    float c_reg = 0.0f;                       // maintained identically on lanes 0..3

    for (int t = 0; t < S_WORDS; t++) {
        // gate on in_gates availability once per 8-row group
        if ((t & 7) == 0) {
            const unsigned int* fl = flags + (t >> 3);
            while (LD_AGENT(fl) < 2u) {}
        }

        // prefetch this unit's 4 input-gate contributions (lanes 0..3); each of
        // lanes 0..3 gets the full set to run the elementwise tail redundantly.
        float ing0 = 0.f, ing1 = 0.f, ing2 = 0.f, ing3 = 0.f;
        if (l < 4) {
            const float* ig = in_gates + (size_t)t * GW + unit;
            ing0 = LD_AGENT(ig + 0 * HDIM);
            ing1 = LD_AGENT(ig + 1 * HDIM);
            ing2 = LD_AGENT(ig + 2 * HDIM);
            ing3 = LD_AGENT(ig + 3 * HDIM);
        }

        // incremental depth-1 poll of this wave's 128-entry slice of our mirror
        const unsigned long long* slot = ring_my + (size_t)(t % 3) * HDIM + v * 128;
        unsigned long long a0 = 0, a1 = 0;
        bool ok0 = false, ok1 = false;
        do {
            if (!ok0) {
                a0 = LD_AGENT(slot + l);
                ok0 = ((unsigned)(a0 >> 32) == (unsigned)t);
            }
            if (!ok1) {
                a1 = LD_AGENT(slot + 64 + l);
                ok1 = ((unsigned)(a1 >> 32) == (unsigned)t);
            }
        } while (!__all(ok0 && ok1));
        {
            union { unsigned u32; float f; } c0, c1;
            c0.u32 = (unsigned)a0; c1.u32 = (unsigned)a1;
            hbb[t & 1][v * 128 + l]      = c0.f;
            hbb[t & 1][v * 128 + 64 + l] = c1.f;
        }
        __syncthreads();                      // single barrier per step

        // all 4 gates of this unit over full K: 64 FMA/lane
        float acc0 = 0.f, acc1 = 0.f, acc2 = 0.f, acc3 = 0.f;
        const float* hb = hbb[t & 1];
        #pragma unroll
        for (int cc = 0; cc < 4; cc++) {
            f32x4 hv = *(const f32x4*)&hb[cc * 256 + l * 4];
            #pragma unroll
            for (int e = 0; e < 4; e++) {
                acc0 = fmaf(w[0][cc][e], hv[e], acc0);
                acc1 = fmaf(w[1][cc][e], hv[e], acc1);
                acc2 = fmaf(w[2][cc][e], hv[e], acc2);
                acc3 = fmaf(w[3][cc][e], hv[e], acc3);
            }
        }
        #pragma unroll
        for (int off = 32; off >= 1; off >>= 1) {   // butterfly allreduce:
            acc0 += __shfl_xor(acc0, off, 64);      // all lanes end with totals
            acc1 += __shfl_xor(acc1, off, 64);
            acc2 += __shfl_xor(acc2, off, 64);
            acc3 += __shfl_xor(acc3, off, 64);
        }

        if (l < 4) {                          // redundant elementwise on lanes 0..3
            float iv = sigm(acc0 + ing0);
            float fv = sigm(acc1 + ing1);
            float gv = tanh_fast(acc2 + ing2);
            float ov = sigm(acc3 + ing3);
            c_reg = fv * c_reg + iv * gv;
            float h = ov * tanh_fast(c_reg);
            union { float f; unsigned u32; } cv; cv.f = h;
            unsigned long long pv =
                ((unsigned long long)(unsigned)(t + 1) << 32) | (unsigned long long)cv.u32;
            // lane l publishes to mirror l: ONE store instruction, 4 mirrors
            __hip_atomic_store(ring + (size_t)l * RING_U64
                                    + (size_t)((t + 1) % 3) * HDIM + unit, pv,
                               __ATOMIC_RELAXED, __HIP_MEMORY_SCOPE_AGENT);
            if (l == 0) out[(size_t)t * HDIM + unit] = h;
        }
        // No trailing barrier: hbb double-buffered; wave v rewrites
        // hbb[t&1][slice v] at t+2 only after detecting h(t+2) tags, which
        // transitively implies all units published h(t+1), which implies every
        // sibling wave passed barrier(t+1), i.e. finished step t's hbb reads.
    }
}

extern "C" void kernel_launch(void* const* d_in, const int* in_sizes, int n_in,
                              void* d_out, int out_size, void* d_ws, size_t ws_size,
                              hipStream_t stream) {
    const int* word_idxs = (const int*)d_in[0];
    const int* char_idxs = (const int*)d_in[1];
    const int* char_lens = (const int*)d_in[2];
    const float* char_emb = (const float*)d_in[3];
    const float* word_emb = (const float*)d_in[4];
    const float* Wih_c = (const float*)d_in[5];
    const float* Whh_c = (const float*)d_in[6];
    const float* bih_c = (const float*)d_in[7];
    const float* bhh_c = (const float*)d_in[8];
    const float* Wih_w = (const float*)d_in[9];
    const float* Whh_w = (const float*)d_in[10];
    const float* bih_w = (const float*)d_in[11];
    const float* bhh_w = (const float*)d_in[12];

    char* ws = (char*)d_ws;
    float*  in_gates = (float*)(ws + IN_GATES_OFF);
    float*  last     = (float*)(ws + LAST_OFF);
    float2* WT2c     = (float2*)(ws + WT2C_OFF);
    unsigned long long* ring = (unsigned long long*)(ws + RING_OFF);
    unsigned int* flags      = (unsigned int*)(ws + FLAGS_OFF);

    hipLaunchKernelGGL(prep_c_kernel, dim3(1024), dim3(256), 0, stream,
                       Wih_c, Whh_c, WT2c);
    hipLaunchKernelGGL(char_lstm_kernel, dim3(256), dim3(1024), 0, stream,
                       char_idxs, char_lens, char_emb, bih_c, bhh_c, WT2c, last);
    // ring mirrors + flags alias WT2c — zero only after char_lstm consumed the
    // weights. All mirrors' slot0 = {tag=0, h=0} (valid t=0 input); slots 1/2 +
    // flags start at 0.
    hipMemsetAsync(ws + RING_OFF, 0,
                   NMIR * RING_U64 * sizeof(unsigned long long) + 256 * sizeof(unsigned int),
                   stream);
    hipLaunchKernelGGL(fused_word_kernel, dim3(NWG_RNN + NWB_WIN), dim3(512), 0, stream,
                       Whh_w, word_idxs, word_emb, last, Wih_w, bih_w, bhh_w,
                       in_gates, ring, flags, (float*)d_out);
}

// Round 8
// 5536.216 us; speedup vs baseline: 1.0878x; 1.0878x over previous
//
#include <hip/hip_runtime.h>
#include <stdint.h>

// Problem constants (from reference)
#define S_WORDS 2048
#define LMAX    16
#define CE      256
#define WE      512
#define HDIM    1024
#define GC      1024   // 4*CE
#define GW      4096   // 4*HDIM
#define KW      768    // WE + CE
#define NWG_RNN 128    // recurrence WGs: 8 units each, 1 unit per wave
#define NWB_WIN 512    // fused wordin producer blocks (2 per 8-row group)
#define NMIR    4      // ring mirrors (fan-in reduction 128 -> 32 pollers/line)
#define RING_U64 (3 * HDIM)   // u64 per mirror (3 slots x 1024)

// Workspace layout (bytes) — high-water 50,331,648 (48 MiB), same as v12.
// NEW: the char weight copies (8 XCD-local replicas, 16 MiB) alias the FIRST
// 16 MiB of in_gates — in_gates is dead until the fused kernel launches, and
// char retires before wordin's first store (stream-serial). Zero growth.
#define IN_GATES_OFF 0                       // 2048*4096 fp32 = 33554432
#define WTREP_OFF    0                       // 8 copies * 256*1024 float2 = 16 MiB (prelude only)
#define LAST_OFF     33554432                // 2048*256 fp32  =  2097152
#define RINGREG_OFF  35651584                // old WT2c region: ring mirrors + flags
#define WT2W_OFF     37748736                // 384*4096 float2 = 12582912
#define RING_OFF     RINGREG_OFF             // 4 mirrors * 3 slots * 1024 u64 = 98304
#define FLAGS_OFF    (RING_OFF + NMIR * RING_U64 * 8)  // 256 u32 = 1024

typedef float f32x4 __attribute__((ext_vector_type(4)));

#define LD_AGENT(p) __hip_atomic_load((p), __ATOMIC_RELAXED, __HIP_MEMORY_SCOPE_AGENT)

static __device__ __forceinline__ float sigm(float x) { return 1.0f / (1.0f + __expf(-x)); }
static __device__ __forceinline__ float tanh_fast(float x) {
    float ax = fminf(fabsf(x), 15.0f);
    float e  = __expf(2.0f * ax);
    float t  = (e - 1.0f) / (e + 1.0f);
    return copysignf(t, x);
}

// ---------- prep: transposed k-major float2 pairs, 8 XCD-local replicas ----------
__global__ void prep_c_kernel(const float* __restrict__ Wih,
                              const float* __restrict__ Whh,
                              float2* __restrict__ WTrep) {
    int idx = blockIdx.x * blockDim.x + threadIdx.x;   // 256*1024
    if (idx >= 256 * GC) return;
    int kp = idx >> 10, row = idx & (GC - 1);
    int k = kp * 2;
    float2 v;
    if (k < CE) { v.x = Wih[row * CE + k];      v.y = Wih[row * CE + k + 1]; }
    else        { v.x = Whh[row * CE + k - CE]; v.y = Whh[row * CE + k - CE + 1]; }
    #pragma unroll
    for (int c = 0; c < 8; c++)
        WTrep[(size_t)c * (256 * GC) + idx] = v;       // 8 coalesced store streams
}

__global__ void prep_w_kernel(const float* __restrict__ Wih,
                              float2* __restrict__ WT2w) {
    int idx = blockIdx.x * blockDim.x + threadIdx.x;   // 384*4096
    if (idx >= 384 * GW) return;
    int kp = idx >> 12, row = idx & (GW - 1);
    float2 v;
    v.x = Wih[row * KW + 2 * kp];
    v.y = Wih[row * KW + 2 * kp + 1];
    WT2w[idx] = v;
}

// ---------- char LSTM v14: gate-split + XCD-local weights + prefetch + tmax ----------
// Gate-split (v12, proven): thread (g, j) = (tid>>8, tid&255) owns gate g of
// unit j over the FULL K=512; 4 waves/SIMD; gates exchanged via padded LDS;
// elementwise + c-state thread-local (thread (g,j) owns words 2g, 2g+1).
// v14: weights read from the XCD-local replica (blockIdx.x & 7 matches the
// round-robin block->XCD mapping) — every weight load is a local-L2 hit
// (~200 cy) instead of ~7/8 remote-MALL (~500-700 cy), which the 2-deep
// rotating prefetch NOW covers. Plus block-uniform tmax early-exit (E~14.8/16).
// Final iteration's prefetch over-reads <=24 KB past the copy (copy c+1 or,
// for c=7, the tail of the in_gates region — readable workspace, values dead).
__global__ void __launch_bounds__(1024, 1) char_lstm_kernel(
    const int* __restrict__ char_idxs,        // [2048][16]
    const int* __restrict__ char_lens,        // [2048]
    const float* __restrict__ char_emb,       // [256][256]
    const float* __restrict__ bih,            // [1024]
    const float* __restrict__ bhh,            // [1024]
    const float2* __restrict__ WTrep,         // [8][256][1024] k-pair replicas
    float* __restrict__ last_out)             // [2048][256]
{
    __shared__ float xh[8][2 * CE];           // 16 KB: [word][x(256) | h(256)]
    __shared__ float gex[4][256][9];          // 36 KB (pad 9 breaks bank aliasing)
    const int j = threadIdx.x & 255;          // unit
    const int g = threadIdx.x >> 8;           // gate 0..3; also word-pair owner
    const int wbase = blockIdx.x * 8;

    const float bias = bih[g * CE + j] + bhh[g * CE + j];   // own gate row only

    int len[2];
    float c[2] = {0.0f, 0.0f};
    len[0] = char_lens[wbase + 2 * g];
    len[1] = char_lens[wbase + 2 * g + 1];
    // block-uniform max len (all threads read the same 8 lens -> same tmax)
    int tmax = 1;
    #pragma unroll
    for (int w = 0; w < 8; w++) {
        int lw = char_lens[wbase + w];
        tmax = lw > tmax ? lw : tmax;
    }
    xh[2 * g][CE + j]     = 0.0f;             // h_{-1} = 0 (words 2g, 2g+1)
    xh[2 * g + 1][CE + j] = 0.0f;

    // XCD-local weight replica for this block
    const float2* __restrict__ wrow =
        WTrep + (size_t)(blockIdx.x & 7) * (256 * GC) + g * CE + j;

    for (int t = 0; t < tmax; t++) {
        // gather x(t) for this thread's 2 words
        {
            int ci0 = char_idxs[(wbase + 2 * g) * LMAX + t];
            int ci1 = char_idxs[(wbase + 2 * g + 1) * LMAX + t];
            xh[2 * g][j]     = char_emb[ci0 * CE + j];
            xh[2 * g + 1][j] = char_emb[ci1 * CE + j];
        }
        __syncthreads();                      // B1: x(t) + h(t-1) visible

        float acc[8];
        #pragma unroll
        for (int w = 0; w < 8; w++) acc[w] = 0.0f;

        // 2-deep rotating prefetch: (c0,c1)=kq, (d0,d1)=kq+1 in flight->use
        float2 c0 = wrow[0 * GC], c1 = wrow[1 * GC];
        float2 d0 = wrow[2 * GC], d1 = wrow[3 * GC];
        const float2* wp = wrow + 4 * GC;
        for (int kq = 0; kq < 128; kq += 2) {
            float2 e0 = wp[0 * GC], e1 = wp[1 * GC];      // prefetch kq+2
            float2 f0 = wp[2 * GC], f1 = wp[3 * GC];      // prefetch kq+3
            wp += 4 * GC;                                  // (last iter: dead over-read)
            #pragma unroll
            for (int w = 0; w < 8; w++) {
                f32x4 xv = *(const f32x4*)&xh[w][4 * kq];  // wave-broadcast
                acc[w] = fmaf(c0.x, xv[0],
                         fmaf(c0.y, xv[1],
                         fmaf(c1.x, xv[2],
                         fmaf(c1.y, xv[3], acc[w]))));
            }
            #pragma unroll
            for (int w = 0; w < 8; w++) {
                f32x4 xv = *(const f32x4*)&xh[w][4 * kq + 4];
                acc[w] = fmaf(d0.x, xv[0],
                         fmaf(d0.y, xv[1],
                         fmaf(d1.x, xv[2],
                         fmaf(d1.y, xv[3], acc[w]))));
            }
            c0 = e0; c1 = e1; d0 = f0; d1 = f1;
        }

        #pragma unroll
        for (int w = 0; w < 8; w++) gex[g][j][w] = acc[w] + bias;
        __syncthreads();                      // B2: gex ready; all xh reads done

        // elementwise for words 2g, 2g+1 (c-state thread-local)
        #pragma unroll
        for (int ww = 0; ww < 2; ww++) {
            int w = 2 * g + ww;
            float gi = gex[0][j][w];
            float gf = gex[1][j][w];
            float gg = gex[2][j][w];
            float go = gex[3][j][w];
            float iv = sigm(gi);
            float fv = sigm(gf);
            float gv = tanhf(gg);
            float ov = sigm(go);
            c[ww] = fv * c[ww] + iv * gv;
            float h = ov * tanhf(c[ww]);
            xh[w][CE + j] = h;                // read by FMA(t+1) after B1(t+1)
            if (t == len[ww] - 1) last_out[(wbase + w) * CE + j] = h;
        }
    }
}

// ---------- fused word-LSTM: wordin producers + persistent recurrence (v9 rnn) ----------
// rnn = exact v9 (mirrored ring, single barrier, depth-1 incremental poll —
// proven 4.51-4.59 ms). wordin = exact v12 (transposed WT2w): v13's raw-Wih_w
// read was lane-strided (64 lines/instr, 16x request amplification) and
// congested the MALL, inflating the rnn's polls 12%. Transposed layout is
// mandatory; prep_w costs only ~30 us.
__global__ void __launch_bounds__(512, 2) fused_word_kernel(
    const float* __restrict__ Whh,            // [4096][1024]
    const int* __restrict__ word_idxs,
    const float* __restrict__ word_emb,       // [50000][512]
    const float* __restrict__ last,           // [2048][256]
    const float2* __restrict__ WT2w,          // [384][4096] k-pairs
    const float* __restrict__ bih,            // [4096]
    const float* __restrict__ bhh,            // [4096]
    float* __restrict__ in_gates,             // [2048][4096]
    unsigned long long* __restrict__ ring,    // [NMIR][3][1024] tagged h
    unsigned int* __restrict__ flags,         // [256] row-group ready counters
    float* __restrict__ out)                  // [2048][1024]
{
    __shared__ float smem[8 * KW];            // 24 KB (wordin xh / rnn hbb overlay)
    const int tid = threadIdx.x;

    if (blockIdx.x >= NWG_RNN) {
        // ---------------- wordin producer role ----------------
        const int nb    = blockIdx.x - NWG_RNN;  // 0..511
        const int grp   = nb >> 1;               // 0..255: rows 8*grp..8*grp+8
        const int half  = nb & 1;
        const int jj    = tid & 255;
        const int gh    = tid >> 8;              // 0/1
        const int rb2   = half * 2 + gh;         // gate quarter 0..3
        const int wbase = grp * 8;
        float (*xh)[KW] = (float(*)[KW])smem;

        for (int w = 0; w < 8; w++) {
            int wi = word_idxs[wbase + w];
            xh[w][tid] = word_emb[(size_t)wi * WE + tid];
            if (tid < 256) xh[w][WE + tid] = last[(wbase + w) * CE + tid];
        }
        __syncthreads();

        float acc[4][8];
        #pragma unroll
        for (int g = 0; g < 4; g++)
            #pragma unroll
            for (int w = 0; w < 8; w++) acc[g][w] = 0.0f;

        for (int kp = 0; kp < KW / 2; kp++) {    // 384 pairs
            float2 wv[4];
            #pragma unroll
            for (int g = 0; g < 4; g++) wv[g] = WT2w[(size_t)kp * GW + rb2 * GC + g * CE + jj];
            #pragma unroll
            for (int w = 0; w < 8; w++) {
                float2 xv = *(const float2*)&xh[w][2 * kp];
                #pragma unroll
                for (int g = 0; g < 4; g++)
                    acc[g][w] = fmaf(wv[g].y, xv.y, fmaf(wv[g].x, xv.x, acc[g][w]));
            }
        }

        // write-through (agent-scope) stores so the recurrence's bypassing loads
        // see them without any cache-coherence dance
        #pragma unroll
        for (int g = 0; g < 4; g++) {
            int row = rb2 * GC + g * CE + jj;
            float bias = bih[row] + bhh[row];
            #pragma unroll
            for (int w = 0; w < 8; w++)
                __hip_atomic_store(in_gates + (size_t)(wbase + w) * GW + row,
                                   acc[g][w] + bias,
                                   __ATOMIC_RELAXED, __HIP_MEMORY_SCOPE_AGENT);
        }
        __syncthreads();   // drains vmcnt -> all stores retired
        if (tid == 0)
            __hip_atomic_fetch_add(flags + grp, 1u,
                                   __ATOMIC_RELEASE, __HIP_MEMORY_SCOPE_AGENT);
        return;
    }

    // ---------------- recurrence role (EXACT v9) ----------------
    const int v = tid >> 6;                   // wave 0..7
    const int l = tid & 63;
    const int unit = blockIdx.x * 8 + v;
    float (*hbb)[HDIM] = (float(*)[HDIM])smem;   // [2][1024] in first 8 KB
    // this WG's poll mirror
    const unsigned long long* ring_my = ring + (size_t)(blockIdx.x & (NMIR - 1)) * RING_U64;

    // resident weights: all 4 gates of this wave's unit, full K
    // w[g][cc] = Whh[g*H+unit][cc*256 + l*4 .. +3]
    f32x4 w[4][4];
    #pragma unroll
    for (int g = 0; g < 4; g++)
        #pragma unroll
        for (int cc = 0; cc < 4; cc++)
            w[g][cc] = *(const f32x4*)(Whh + (size_t)(g * HDIM + unit) * HDIM
                                       + cc * 256 + l * 4);
    #pragma unroll
    for (int g = 0; g < 4; g++)
        #pragma unroll
        for (int cc = 0; cc < 4; cc++)
            asm volatile("" : "+v"(w[g][cc]));

    float c_reg = 0.0f;                       // maintained identically on lanes 0..3

    for (int t = 0; t < S_WORDS; t++) {
        // gate on in_gates availability once per 8-row group
        if ((t & 7) == 0) {
            const unsigned int* fl = flags + (t >> 3);
            while (LD_AGENT(fl) < 2u) {}
        }

        // prefetch this unit's 4 input-gate contributions (lanes 0..3); each of
        // lanes 0..3 gets the full set to run the elementwise tail redundantly.
        float ing0 = 0.f, ing1 = 0.f, ing2 = 0.f, ing3 = 0.f;
        if (l < 4) {
            const float* ig = in_gates + (size_t)t * GW + unit;
            ing0 = LD_AGENT(ig + 0 * HDIM);
            ing1 = LD_AGENT(ig + 1 * HDIM);
            ing2 = LD_AGENT(ig + 2 * HDIM);
            ing3 = LD_AGENT(ig + 3 * HDIM);
        }

        // incremental depth-1 poll of this wave's 128-entry slice of our mirror
        const unsigned long long* slot = ring_my + (size_t)(t % 3) * HDIM + v * 128;
        unsigned long long a0 = 0, a1 = 0;
        bool ok0 = false, ok1 = false;
        do {
            if (!ok0) {
                a0 = LD_AGENT(slot + l);
                ok0 = ((unsigned)(a0 >> 32) == (unsigned)t);
            }
            if (!ok1) {
                a1 = LD_AGENT(slot + 64 + l);
                ok1 = ((unsigned)(a1 >> 32) == (unsigned)t);
            }
        } while (!__all(ok0 && ok1));
        {
            union { unsigned u32; float f; } c0, c1;
            c0.u32 = (unsigned)a0; c1.u32 = (unsigned)a1;
            hbb[t & 1][v * 128 + l]      = c0.f;
            hbb[t & 1][v * 128 + 64 + l] = c1.f;
        }
        __syncthreads();                      // single barrier per step

        // all 4 gates of this unit over full K: 64 FMA/lane
        float acc0 = 0.f, acc1 = 0.f, acc2 = 0.f, acc3 = 0.f;
        const float* hb = hbb[t & 1];
        #pragma unroll
        for (int cc = 0; cc < 4; cc++) {
            f32x4 hv = *(const f32x4*)&hb[cc * 256 + l * 4];
            #pragma unroll
            for (int e = 0; e < 4; e++) {
                acc0 = fmaf(w[0][cc][e], hv[e], acc0);
                acc1 = fmaf(w[1][cc][e], hv[e], acc1);
                acc2 = fmaf(w[2][cc][e], hv[e], acc2);
                acc3 = fmaf(w[3][cc][e], hv[e], acc3);
            }
        }
        #pragma unroll
        for (int off = 32; off >= 1; off >>= 1) {   // butterfly allreduce:
            acc0 += __shfl_xor(acc0, off, 64);      // all lanes end with totals
            acc1 += __shfl_xor(acc1, off, 64);
            acc2 += __shfl_xor(acc2, off, 64);
            acc3 += __shfl_xor(acc3, off, 64);
        }

        if (l < 4) {                          // redundant elementwise on lanes 0..3
            float iv = sigm(acc0 + ing0);
            float fv = sigm(acc1 + ing1);
            float gv = tanh_fast(acc2 + ing2);
            float ov = sigm(acc3 + ing3);
            c_reg = fv * c_reg + iv * gv;
            float h = ov * tanh_fast(c_reg);
            union { float f; unsigned u32; } cv; cv.f = h;
            unsigned long long pv =
                ((unsigned long long)(unsigned)(t + 1) << 32) | (unsigned long long)cv.u32;
            // lane l publishes to mirror l: ONE store instruction, 4 mirrors
            __hip_atomic_store(ring + (size_t)l * RING_U64
                                    + (size_t)((t + 1) % 3) * HDIM + unit, pv,
                               __ATOMIC_RELAXED, __HIP_MEMORY_SCOPE_AGENT);
            if (l == 0) out[(size_t)t * HDIM + unit] = h;
        }
        // No trailing barrier: hbb double-buffered; wave v rewrites
        // hbb[t&1][slice v] at t+2 only after detecting h(t+2) tags, which
        // transitively implies all units published h(t+1), which implies every
        // sibling wave passed barrier(t+1), i.e. finished step t's hbb reads.
    }
}

extern "C" void kernel_launch(void* const* d_in, const int* in_sizes, int n_in,
                              void* d_out, int out_size, void* d_ws, size_t ws_size,
                              hipStream_t stream) {
    const int* word_idxs = (const int*)d_in[0];
    const int* char_idxs = (const int*)d_in[1];
    const int* char_lens = (const int*)d_in[2];
    const float* char_emb = (const float*)d_in[3];
    const float* word_emb = (const float*)d_in[4];
    const float* Wih_c = (const float*)d_in[5];
    const float* Whh_c = (const float*)d_in[6];
    const float* bih_c = (const float*)d_in[7];
    const float* bhh_c = (const float*)d_in[8];
    const float* Wih_w = (const float*)d_in[9];
    const float* Whh_w = (const float*)d_in[10];
    const float* bih_w = (const float*)d_in[11];
    const float* bhh_w = (const float*)d_in[12];

    char* ws = (char*)d_ws;
    float*  in_gates = (float*)(ws + IN_GATES_OFF);
    float2* WTrep    = (float2*)(ws + WTREP_OFF);   // aliases in_gates (prelude only)
    float*  last     = (float*)(ws + LAST_OFF);
    float2* WT2w     = (float2*)(ws + WT2W_OFF);
    unsigned long long* ring = (unsigned long long*)(ws + RING_OFF);
    unsigned int* flags      = (unsigned int*)(ws + FLAGS_OFF);

    hipLaunchKernelGGL(prep_c_kernel, dim3(1024), dim3(256), 0, stream,
                       Wih_c, Whh_c, WTrep);
    hipLaunchKernelGGL(prep_w_kernel, dim3(6144), dim3(256), 0, stream,
                       Wih_w, WT2w);
    hipLaunchKernelGGL(char_lstm_kernel, dim3(256), dim3(1024), 0, stream,
                       char_idxs, char_lens, char_emb, bih_c, bhh_c, WTrep, last);
    // ring mirrors + flags live in the old WT2c region (no aliasing hazards now).
    // All mirrors' slot0 = {tag=0, h=0} (valid t=0 input); slots 1/2 + flags = 0.
    hipMemsetAsync(ws + RING_OFF, 0,
                   NMIR * RING_U64 * sizeof(unsigned long long) + 256 * sizeof(unsigned int),
                   stream);
    hipLaunchKernelGGL(fused_word_kernel, dim3(NWG_RNN + NWB_WIN), dim3(512), 0, stream,
                       Whh_w, word_idxs, word_emb, last, WT2w, bih_w, bhh_w,
                       in_gates, ring, flags, (float*)d_out);
}

// Round 10
// 5359.171 us; speedup vs baseline: 1.1238x; 1.0330x over previous
//
#include <hip/hip_runtime.h>
#include <stdint.h>

// Problem constants (from reference)
#define S_WORDS 2048
#define LMAX    16
#define CE      256
#define WE      512
#define HDIM    1024
#define GC      1024   // 4*CE
#define GW      4096   // 4*HDIM
#define KW      768    // WE + CE
#define NWG_RNN  128   // recurrence WGs: 8 units each, 1 unit per wave
#define NWB_CHAR 256   // char producer blocks (8 words each == 1 wordin group)
#define NWB_WIN  512   // wordin producer blocks (2 per 8-row group)
#define NMIR    4      // ring mirrors
#define RING_U64 (3 * HDIM)   // u64 per mirror (3 slots x 1024)

// Workspace layout (bytes) — high-water 50,331,648 (48 MiB).
// WT2c aliases in_gates rows 1920..2047 (2 MiB tail). Writers of those rows
// are wordin groups 240..255 only, and they gate on char_all==256 (all char
// blocks done reading weights). Ring + flags live in the old WT2c region
// (35651584), which nothing else touches now. prep_c/prep_w run as PRIOR
// dispatches -> weight visibility via kernel-boundary ordering (no in-kernel
// transpose, no prep flag — v15's hang-risk elements removed).
#define IN_GATES_OFF 0                       // 2048*4096 fp32 = 33554432
#define WT2C_OFF     31457280                // in_gates rows 1920.. (gated alias)
#define LAST_OFF     33554432                // 2048*256 fp32 = 2097152
#define RING_OFF     35651584                // 4 mirrors * 3 slots * 1024 u64 = 98304
#define FLAGSW_OFF   (RING_OFF + NMIR * RING_U64 * 8)   // 256 u32
#define FLAGSC_OFF   (FLAGSW_OFF + 1024)                // 256 u32
#define CALL_OFF     (FLAGSC_OFF + 1024)                // char_all (own line)
#define CTRL_BYTES   (NMIR * RING_U64 * 8 + 1024 + 1024 + 128)
#define WT2W_OFF     37748736                // 384*4096 float2 = 12582912 (ends 48 MiB)

typedef float f32x4 __attribute__((ext_vector_type(4)));

#define LD_AGENT(p) __hip_atomic_load((p), __ATOMIC_RELAXED, __HIP_MEMORY_SCOPE_AGENT)

static __device__ __forceinline__ float sigm(float x) { return 1.0f / (1.0f + __expf(-x)); }
static __device__ __forceinline__ float tanh_fast(float x) {
    float ax = fminf(fabsf(x), 15.0f);
    float e  = __expf(2.0f * ax);
    float t  = (e - 1.0f) / (e + 1.0f);
    return copysignf(t, x);
}

// ---------- prep: transposed k-major float2 pairs (separate dispatches) ----------
__global__ void prep_c_kernel(const float* __restrict__ Wih,
                              const float* __restrict__ Whh,
                              float2* __restrict__ WT2c) {
    int idx = blockIdx.x * blockDim.x + threadIdx.x;   // 256*1024
    if (idx >= 256 * GC) return;
    int kp = idx >> 10, row = idx & (GC - 1);
    int k = kp * 2;
    float2 v;
    if (k < CE) { v.x = Wih[row * CE + k];      v.y = Wih[row * CE + k + 1]; }
    else        { v.x = Whh[row * CE + k - CE]; v.y = Whh[row * CE + k - CE + 1]; }
    WT2c[idx] = v;
}

__global__ void prep_w_kernel(const float* __restrict__ Wih,
                              float2* __restrict__ WT2w) {
    int idx = blockIdx.x * blockDim.x + threadIdx.x;   // 384*4096
    if (idx >= 384 * GW) return;
    int kp = idx >> 12, row = idx & (GW - 1);
    float2 v;
    v.x = Wih[row * KW + 2 * kp];
    v.y = Wih[row * KW + 2 * kp + 1];
    WT2w[idx] = v;
}

// ---------- mega-kernel: char + wordin + rnn (v16) ----------
// Roles by blockIdx (each waiter depends only on wait-free or proven-pattern
// producers; dependency depth 2):
//   rnn    0..127:   exact v9 recurrence; waits flagsW (higher-blockIdx churn —
//                    the pattern proven across v7-v14)
//   char   128..383: v12 gate-split char LSTM, 8 words/block, NO waits
//   wordin 384..895: waits flagsC[grp]==1 (char block grp, lower blockIdx,
//                    wait-free); grp>=240 additionally waits char_all==256
//                    before overwriting the WT2c alias region
__global__ void __launch_bounds__(512, 2) mega_kernel(
    const int* __restrict__ word_idxs,
    const int* __restrict__ char_idxs,
    const int* __restrict__ char_lens,
    const float* __restrict__ char_emb,       // [256][256]
    const float* __restrict__ word_emb,       // [50000][512]
    const float* __restrict__ bih_c,          // [1024]
    const float* __restrict__ bhh_c,          // [1024]
    const float* __restrict__ Whh_w,          // [4096][1024]
    const float* __restrict__ bih_w,          // [4096]
    const float* __restrict__ bhh_w,          // [4096]
    const float2* __restrict__ WT2c,          // [256][1024] k-pairs (in_gates tail)
    const float2* __restrict__ WT2w,          // [384][4096] k-pairs
    float* __restrict__ last,                 // [2048][256]
    float* __restrict__ in_gates,             // [2048][4096]
    unsigned long long* __restrict__ ring,    // [NMIR][3][1024] tagged h
    unsigned int* __restrict__ flagsW,        // [256] wordin-group done (==2)
    unsigned int* __restrict__ flagsC,        // [256] char-group done (==1)
    unsigned int* __restrict__ char_all,      // all-char counter (==256)
    float* __restrict__ out)                  // [2048][1024]
{
    __shared__ float smem[13312];             // 52 KB: max(char 52K, wordin 24K, rnn 8K)
    const int tid = threadIdx.x;

    if (blockIdx.x >= NWG_RNN + NWB_CHAR) {
        // ---------------- wordin producer role ----------------
        const int nb    = blockIdx.x - (NWG_RNN + NWB_CHAR);  // 0..511
        const int grp   = nb >> 1;               // 0..255: rows 8*grp..8*grp+8
        const int half  = nb & 1;
        const int jj    = tid & 255;
        const int gh    = tid >> 8;              // 0/1
        const int rb2   = half * 2 + gh;         // gate quarter 0..3
        const int wbase = grp * 8;
        float (*xh)[KW] = (float(*)[KW])smem;

        if (tid == 0) {
            while (LD_AGENT(flagsC + grp) < 1u) { __builtin_amdgcn_s_sleep(2); }
            if (grp >= 240)                      // writes in_gates rows >=1920 (WT2c alias)
                while (LD_AGENT(char_all) < (unsigned)NWB_CHAR) { __builtin_amdgcn_s_sleep(2); }
        }
        __syncthreads();

        for (int w = 0; w < 8; w++) {
            int wi = word_idxs[wbase + w];
            xh[w][tid] = word_emb[(size_t)wi * WE + tid];
            if (tid < 256) xh[w][WE + tid] = last[(wbase + w) * CE + tid];
        }
        __syncthreads();

        float acc[4][8];
        #pragma unroll
        for (int g = 0; g < 4; g++)
            #pragma unroll
            for (int w = 0; w < 8; w++) acc[g][w] = 0.0f;

        for (int kp = 0; kp < KW / 2; kp++) {    // 384 pairs
            float2 wv[4];
            #pragma unroll
            for (int g = 0; g < 4; g++) wv[g] = WT2w[(size_t)kp * GW + rb2 * GC + g * CE + jj];
            #pragma unroll
            for (int w = 0; w < 8; w++) {
                float2 xv = *(const float2*)&xh[w][2 * kp];
                #pragma unroll
                for (int g = 0; g < 4; g++)
                    acc[g][w] = fmaf(wv[g].y, xv.y, fmaf(wv[g].x, xv.x, acc[g][w]));
            }
        }

        #pragma unroll
        for (int g = 0; g < 4; g++) {
            int row = rb2 * GC + g * CE + jj;
            float bias = bih_w[row] + bhh_w[row];
            #pragma unroll
            for (int w = 0; w < 8; w++)
                __hip_atomic_store(in_gates + (size_t)(wbase + w) * GW + row,
                                   acc[g][w] + bias,
                                   __ATOMIC_RELAXED, __HIP_MEMORY_SCOPE_AGENT);
        }
        __syncthreads();   // drains vmcnt -> all stores retired
        if (tid == 0)
            __hip_atomic_fetch_add(flagsW + grp, 1u,
                                   __ATOMIC_RELEASE, __HIP_MEMORY_SCOPE_AGENT);
        return;
    }

    if (blockIdx.x >= NWG_RNN) {
        // ---------------- char producer role (gate-split, 8 words, no waits) --------
        const int cb = blockIdx.x - NWG_RNN;     // 0..255 == wordin group id
        const int wbase = cb * 8;
        const int j = tid & 255;                 // unit
        const int p = tid >> 8;                  // 0/1: gate rows 2p, 2p+1
        float (*cxh)[2 * CE]  = (float(*)[2 * CE])smem;                 // [8][512] 16 KB
        float (*cgex)[256][9] = (float(*)[256][9])(smem + 8 * 2 * CE);  // [4][256][9] 36 KB

        const float bias0 = bih_c[(2 * p) * CE + j]     + bhh_c[(2 * p) * CE + j];
        const float bias1 = bih_c[(2 * p + 1) * CE + j] + bhh_c[(2 * p + 1) * CE + j];

        int len[4];
        float c[4] = {0.f, 0.f, 0.f, 0.f};       // c-state for words 4p..4p+3
        #pragma unroll
        for (int ww = 0; ww < 4; ww++) len[ww] = char_lens[wbase + 4 * p + ww];
        int tmax = 1;
        #pragma unroll
        for (int w = 0; w < 8; w++) {
            int lw = char_lens[wbase + w];
            tmax = lw > tmax ? lw : tmax;
        }
        #pragma unroll
        for (int ww = 0; ww < 4; ww++) cxh[4 * p + ww][CE + j] = 0.0f;   // h_{-1}=0

        const float2* __restrict__ wrow0 = WT2c + (2 * p) * CE + j;
        const float2* __restrict__ wrow1 = WT2c + (2 * p + 1) * CE + j;

        for (int t = 0; t < tmax; t++) {
            #pragma unroll
            for (int ww = 0; ww < 4; ww++) {
                int w = 4 * p + ww;
                int ci = char_idxs[(wbase + w) * LMAX + t];
                cxh[w][j] = char_emb[ci * CE + j];
            }
            __syncthreads();                     // B1: x(t) + h(t-1) visible

            float a0[8], a1[8];
            #pragma unroll
            for (int w = 0; w < 8; w++) { a0[w] = 0.0f; a1[w] = 0.0f; }

            #pragma unroll 2
            for (int kp = 0; kp < CE; kp++) {
                float2 wv0 = wrow0[(size_t)kp * GC];
                float2 wv1 = wrow1[(size_t)kp * GC];
                #pragma unroll
                for (int w = 0; w < 8; w++) {
                    float2 xv = *(const float2*)&cxh[w][2 * kp];   // broadcast
                    a0[w] = fmaf(wv0.y, xv.y, fmaf(wv0.x, xv.x, a0[w]));
                    a1[w] = fmaf(wv1.y, xv.y, fmaf(wv1.x, xv.x, a1[w]));
                }
            }

            #pragma unroll
            for (int w = 0; w < 8; w++) {
                cgex[2 * p][j][w]     = a0[w] + bias0;
                cgex[2 * p + 1][j][w] = a1[w] + bias1;
            }
            __syncthreads();                     // B2: gex ready; all cxh reads done

            #pragma unroll
            for (int ww = 0; ww < 4; ww++) {
                int w = 4 * p + ww;
                float gi = cgex[0][j][w];
                float gf = cgex[1][j][w];
                float gg = cgex[2][j][w];
                float go = cgex[3][j][w];
                float iv = sigm(gi);
                float fv = sigm(gf);
                float gv = tanhf(gg);
                float ov = sigm(go);
                c[ww] = fv * c[ww] + iv * gv;
                float h = ov * tanhf(c[ww]);
                cxh[w][CE + j] = h;              // read by FMA(t+1) after B1(t+1)
                if (t == len[ww] - 1)
                    __hip_atomic_store(last + (wbase + w) * CE + j, h,
                                       __ATOMIC_RELAXED, __HIP_MEMORY_SCOPE_AGENT);
            }
        }

        __syncthreads();                         // drains vmcnt (last stores retired)
        if (tid == 0) {
            __hip_atomic_fetch_add(flagsC + cb, 1u,
                                   __ATOMIC_RELEASE, __HIP_MEMORY_SCOPE_AGENT);
            __hip_atomic_fetch_add(char_all, 1u,
                                   __ATOMIC_RELEASE, __HIP_MEMORY_SCOPE_AGENT);
        }
        return;
    }

    // ---------------- recurrence role (EXACT v9) ----------------
    const int v = tid >> 6;                   // wave 0..7
    const int l = tid & 63;
    const int unit = blockIdx.x * 8 + v;
    float (*hbb)[HDIM] = (float(*)[HDIM])smem;   // [2][1024] in first 8 KB
    const unsigned long long* ring_my = ring + (size_t)(blockIdx.x & (NMIR - 1)) * RING_U64;

    // resident weights: all 4 gates of this wave's unit, full K
    f32x4 w[4][4];
    #pragma unroll
    for (int g = 0; g < 4; g++)
        #pragma unroll
        for (int cc = 0; cc < 4; cc++)
            w[g][cc] = *(const f32x4*)(Whh_w + (size_t)(g * HDIM + unit) * HDIM
                                       + cc * 256 + l * 4);
    #pragma unroll
    for (int g = 0; g < 4; g++)
        #pragma unroll
        for (int cc = 0; cc < 4; cc++)
            asm volatile("" : "+v"(w[g][cc]));

    float c_reg = 0.0f;                       // maintained identically on lanes 0..3

    for (int t = 0; t < S_WORDS; t++) {
        if ((t & 7) == 0) {
            const unsigned int* fl = flagsW + (t >> 3);
            while (LD_AGENT(fl) < 2u) { __builtin_amdgcn_s_sleep(8); }
        }

        float ing0 = 0.f, ing1 = 0.f, ing2 = 0.f, ing3 = 0.f;
        if (l < 4) {
            const float* ig = in_gates + (size_t)t * GW + unit;
            ing0 = LD_AGENT(ig + 0 * HDIM);
            ing1 = LD_AGENT(ig + 1 * HDIM);
            ing2 = LD_AGENT(ig + 2 * HDIM);
            ing3 = LD_AGENT(ig + 3 * HDIM);
        }

        // incremental depth-1 poll of this wave's 128-entry slice of our mirror
        const unsigned long long* slot = ring_my + (size_t)(t % 3) * HDIM + v * 128;
        unsigned long long a0 = 0, a1 = 0;
        bool ok0 = false, ok1 = false;
        do {
            if (!ok0) {
                a0 = LD_AGENT(slot + l);
                ok0 = ((unsigned)(a0 >> 32) == (unsigned)t);
            }
            if (!ok1) {
                a1 = LD_AGENT(slot + 64 + l);
                ok1 = ((unsigned)(a1 >> 32) == (unsigned)t);
            }
        } while (!__all(ok0 && ok1));
        {
            union { unsigned u32; float f; } c0, c1;
            c0.u32 = (unsigned)a0; c1.u32 = (unsigned)a1;
            hbb[t & 1][v * 128 + l]      = c0.f;
            hbb[t & 1][v * 128 + 64 + l] = c1.f;
        }
        __syncthreads();                      // single barrier per step

        float acc0 = 0.f, acc1 = 0.f, acc2 = 0.f, acc3 = 0.f;
        const float* hb = hbb[t & 1];
        #pragma unroll
        for (int cc = 0; cc < 4; cc++) {
            f32x4 hv = *(const f32x4*)&hb[cc * 256 + l * 4];
            #pragma unroll
            for (int e = 0; e < 4; e++) {
                acc0 = fmaf(w[0][cc][e], hv[e], acc0);
                acc1 = fmaf(w[1][cc][e], hv[e], acc1);
                acc2 = fmaf(w[2][cc][e], hv[e], acc2);
                acc3 = fmaf(w[3][cc][e], hv[e], acc3);
            }
        }
        #pragma unroll
        for (int off = 32; off >= 1; off >>= 1) {   // butterfly allreduce
            acc0 += __shfl_xor(acc0, off, 64);
            acc1 += __shfl_xor(acc1, off, 64);
            acc2 += __shfl_xor(acc2, off, 64);
            acc3 += __shfl_xor(acc3, off, 64);
        }

        if (l < 4) {                          // redundant elementwise on lanes 0..3
            float iv = sigm(acc0 + ing0);
            float fv = sigm(acc1 + ing1);
            float gv = tanh_fast(acc2 + ing2);
            float ov = sigm(acc3 + ing3);
            c_reg = fv * c_reg + iv * gv;
            float h = ov * tanh_fast(c_reg);
            union { float f; unsigned u32; } cv; cv.f = h;
            unsigned long long pv =
                ((unsigned long long)(unsigned)(t + 1) << 32) | (unsigned long long)cv.u32;
            __hip_atomic_store(ring + (size_t)l * RING_U64
                                    + (size_t)((t + 1) % 3) * HDIM + unit, pv,
                               __ATOMIC_RELAXED, __HIP_MEMORY_SCOPE_AGENT);
            if (l == 0) out[(size_t)t * HDIM + unit] = h;
        }
        // No trailing barrier: hbb double-buffered (v9 transitive argument).
    }
}

extern "C" void kernel_launch(void* const* d_in, const int* in_sizes, int n_in,
                              void* d_out, int out_size, void* d_ws, size_t ws_size,
                              hipStream_t stream) {
    const int* word_idxs = (const int*)d_in[0];
    const int* char_idxs = (const int*)d_in[1];
    const int* char_lens = (const int*)d_in[2];
    const float* char_emb = (const float*)d_in[3];
    const float* word_emb = (const float*)d_in[4];
    const float* Wih_c = (const float*)d_in[5];
    const float* Whh_c = (const float*)d_in[6];
    const float* bih_c = (const float*)d_in[7];
    const float* bhh_c = (const float*)d_in[8];
    const float* Wih_w = (const float*)d_in[9];
    const float* Whh_w = (const float*)d_in[10];
    const float* bih_w = (const float*)d_in[11];
    const float* bhh_w = (const float*)d_in[12];

    char* ws = (char*)d_ws;
    float*  in_gates = (float*)(ws + IN_GATES_OFF);
    float2* WT2c     = (float2*)(ws + WT2C_OFF);
    float*  last     = (float*)(ws + LAST_OFF);
    float2* WT2w     = (float2*)(ws + WT2W_OFF);
    unsigned long long* ring = (unsigned long long*)(ws + RING_OFF);
    unsigned int* flagsW     = (unsigned int*)(ws + FLAGSW_OFF);
    unsigned int* flagsC     = (unsigned int*)(ws + FLAGSC_OFF);
    unsigned int* char_all   = (unsigned int*)(ws + CALL_OFF);

    // weight transposes: stream-ordered BEFORE the mega kernel (visibility via
    // kernel-boundary release/acquire — no in-kernel prep, no prep flag)
    hipLaunchKernelGGL(prep_c_kernel, dim3(1024), dim3(256), 0, stream,
                       Wih_c, Whh_c, WT2c);
    hipLaunchKernelGGL(prep_w_kernel, dim3(6144), dim3(256), 0, stream,
                       Wih_w, WT2w);
    // zero ring (slot0 tag=0 = valid t=0 h=0) + flagsW + flagsC + char_all
    hipMemsetAsync(ws + RING_OFF, 0, CTRL_BYTES, stream);
    hipLaunchKernelGGL(mega_kernel, dim3(NWG_RNN + NWB_CHAR + NWB_WIN), dim3(512),
                       0, stream,
                       word_idxs, char_idxs, char_lens, char_emb, word_emb,
                       bih_c, bhh_c, Whh_w, bih_w, bhh_w,
                       WT2c, WT2w, last, in_gates,
                       ring, flagsW, flagsC, char_all, (float*)d_out);
}